// Round 6
// baseline (27.376 us; speedup 1.0000x reference)
//
#include <hip/hip_runtime.h>

// Problem: B=4096, N=16, E=512. Outputs: aggregated (B,E) then weights (B,N), f32.
//
// task_anchor @ v_t is a per-b constant across the softmax axis -> dead input
// (softmax shift invariance). Traffic floor: 134.2 MB read + 8.9 MB write.
//
// Structure (R6): one block (4 waves, 256 thr) per b. The 16x512 row tile is
// staged to LDS via global_load_lds (16 B width, no VGPR round-trip): wave w
// streams flat elements [2048w, 2048(w+1)) = rows 4w..4w+3, linear LDS layout.
// VGPR ~50 -> blocks limited only by LDS (32.25 KB -> 4 blocks/CU), with
// blocks at staggered phases (loads in flight vs epilogue) covering HBM
// latency. Scores: per-thread dot2 partials from LDS, 17-shuffle multi-value
// butterfly (verified R4), lds_s[16][4] cross-wave combine. Aggregation
// re-reads the LDS tile (cheap, 69 TB/s pipe). Expert read from HBM once.

#define NB 4096
#define NEXP 16
#define EDIM 512

typedef float f32x2 __attribute__((ext_vector_type(2)));

__global__ __launch_bounds__(256, 4) void meta_attn_kernel(
    const float* __restrict__ expert,   // [B, 16, 512]
    const float* __restrict__ v,        // [640, 1]; v_e = v[0:512]
    float* __restrict__ out_agg,        // [B, 512]
    float* __restrict__ out_w)          // [B, 16]
{
    const int wave = threadIdx.x >> 6;
    const int lane = threadIdx.x & 63;
    const int b = blockIdx.x;

    __shared__ float smem[NEXP * EDIM];   // 32 KB row tile, linear
    __shared__ float lds_s[NEXP][4];      // cross-wave score partials

    // ---- Stage: global -> LDS, 8 x 16B-wide global_load_lds per wave ----
    // Wave w covers flat elements [2048w, 2048(w+1)); chunk i is 1 KB.
    {
        const float* gbase = expert + (size_t)b * (NEXP * EDIM) + wave * 2048;
        float* lbase = smem + wave * 2048;
#pragma unroll
        for (int i = 0; i < 8; ++i) {
            __builtin_amdgcn_global_load_lds(
                (const __attribute__((address_space(1))) void*)(gbase + i * 256 + lane * 4),
                (__attribute__((address_space(3))) void*)(lbase + i * 256),
                16, 0, 0);
        }
    }

    // v reused by every block: regular cached loads (while loads are in flight)
    const int eoff = 128 * wave + 2 * lane;   // this thread's e-slice
    const f32x2 ve = *(const f32x2*)(v + eoff);

    __syncthreads();   // compiler emits s_waitcnt vmcnt(0) before s_barrier

    // ---- Score pass: per-thread dot2 partials from LDS ----
    float cur[NEXP];
#pragma unroll
    for (int n = 0; n < NEXP; ++n) {
        const f32x2 t = *(const f32x2*)(&smem[n * EDIM + eoff]);
        cur[n] = t.x * ve.x + t.y * ve.y;
    }

    // Multi-value butterfly: 16 partials over 64 lanes in 17 shuffles
    // (verified R4). Lane ends owning score rev4(lane&15).
    float t8[8];
    {
        const bool hi = (lane & 1) != 0;
#pragma unroll
        for (int j = 0; j < 8; ++j) {
            const float send = hi ? cur[j] : cur[j + 8];
            const float keep = hi ? cur[j + 8] : cur[j];
            t8[j] = keep + __shfl_xor(send, 1, 64);
        }
    }
    float t4[4];
    {
        const bool hi = (lane & 2) != 0;
#pragma unroll
        for (int j = 0; j < 4; ++j) {
            const float send = hi ? t8[j] : t8[j + 4];
            const float keep = hi ? t8[j + 4] : t8[j];
            t4[j] = keep + __shfl_xor(send, 2, 64);
        }
    }
    float t2[2];
    {
        const bool hi = (lane & 4) != 0;
#pragma unroll
        for (int j = 0; j < 2; ++j) {
            const float send = hi ? t4[j] : t4[j + 2];
            const float keep = hi ? t4[j + 2] : t4[j];
            t2[j] = keep + __shfl_xor(send, 4, 64);
        }
    }
    float t1;
    {
        const bool hi = (lane & 8) != 0;
        const float send = hi ? t2[0] : t2[1];
        const float keep = hi ? t2[1] : t2[0];
        t1 = keep + __shfl_xor(send, 8, 64);
    }
    t1 += __shfl_xor(t1, 16, 64);
    t1 += __shfl_xor(t1, 32, 64);

    // Cross-wave combine
    if (lane < 16) {
        const int idx = ((lane & 1) << 3) | ((lane & 2) << 1) |
                        ((lane & 4) >> 1) | ((lane & 8) >> 3);
        lds_s[idx][wave] = t1;
    }
    __syncthreads();

    float s[NEXP];
#pragma unroll
    for (int n = 0; n < NEXP; ++n)
        s[n] = (lds_s[n][0] + lds_s[n][1]) + (lds_s[n][2] + lds_s[n][3]);

    // Softmax over 16 scores (redundant per thread, no divergence)
    float mx = s[0];
#pragma unroll
    for (int n = 1; n < NEXP; ++n) mx = fmaxf(mx, s[n]);
    float w[NEXP];
    float sum = 0.0f;
#pragma unroll
    for (int n = 0; n < NEXP; ++n) {
        w[n] = __expf(s[n] - mx);
        sum += w[n];
    }
    const float inv = 1.0f / sum;
#pragma unroll
    for (int n = 0; n < NEXP; ++n) w[n] *= inv;

    // ---- Aggregation pass: re-read LDS tile, weighted sum ----
    f32x2 acc = {0.f, 0.f};
#pragma unroll
    for (int n = 0; n < NEXP; ++n) {
        const f32x2 t = *(const f32x2*)(&smem[n * EDIM + eoff]);
        acc.x += w[n] * t.x;
        acc.y += w[n] * t.y;
    }
    *(f32x2*)(out_agg + (size_t)b * EDIM + eoff) = acc;

    // Weights: select chain (compile-time indices) + one coalesced 64 B store
    if (wave == 0) {
        float myw = w[0];
#pragma unroll
        for (int n = 1; n < NEXP; ++n) myw = (lane == n) ? w[n] : myw;
        if (lane < NEXP) out_w[(size_t)b * NEXP + lane] = myw;
    }
}

extern "C" void kernel_launch(void* const* d_in, const int* in_sizes, int n_in,
                              void* d_out, int out_size, void* d_ws, size_t ws_size,
                              hipStream_t stream) {
    // d_in: 0=scene_repr (unused), 1=task_anchor (unused), 2=expert_reprs, 3=v
    const float* expert = (const float*)d_in[2];
    const float* v      = (const float*)d_in[3];
    float* out_agg = (float*)d_out;
    float* out_w   = (float*)d_out + (size_t)NB * EDIM;

    meta_attn_kernel<<<dim3(NB), dim3(256), 0, stream>>>(expert, v, out_agg, out_w);
}